// Round 8
// baseline (204.160 us; speedup 1.0000x reference)
//
#include <hip/hip_runtime.h>
#include <hip/hip_bf16.h>

// B=16, S=2048, D=128 causal attention, pre-scale threshold:
//   A = Q@T^T; A = (A>0.3 ? A : 0); causal -2^32; /sqrt(128); softmax; @V
// fp32 in/out, bf16 MFMA internal. Fixed-max softmax (m=0; post-threshold
// logits in [0,~9]) => partial (oacc, sum-l) accumulators are ADDITIVE.
//
// V8 = V7's compute body (verified 44us, 104 VGPR) with the slot structure
// halved twice:
//  * BQ=128 per 8-wave block (512 thr): S-phase = 4 key-groups x 2 q-halves,
//    PV = 4 d-groups x 2 q-halves. Per-wave regs/ds-ops identical to V7;
//    each 32KB tile-load serves 2x the q-rows => slots/CU 33 -> 17.
//  * 2 barriers/slot (was 3): triple-buffered tiles with DMA issued 2 ahead
//    (after b1, the point where buf (s+2)%3's readers are provably done) +
//    double-buffered P. Counted vmcnt(4).
//  * LDS 128KB => 1 block/CU, grid 256 = CU count, bounds(512,2) keeps the
//    256-VGPR cap (V3/V6's spill trap was the 128 cap — not repeated).
//  * nrm folded in: heavy q-tile = 2 contributors; c1 spins for c0's partial
//    (V3/V5-proven release/acquire protocol; all 256 blocks co-resident).

#define S_LEN 2048
#define D_DIM 128
#define THRESH 0.3f
#define SCALE 0.08838834764831845f   // 1/sqrt(128)

typedef __bf16 bf16x8 __attribute__((ext_vector_type(8)));
typedef __bf16 bf16x4 __attribute__((ext_vector_type(4)));
typedef float f32x4 __attribute__((ext_vector_type(4)));

#define GLD16(g, l)                                                         \
    __builtin_amdgcn_global_load_lds(                                       \
        (const __attribute__((address_space(1))) unsigned int*)(g),         \
        (__attribute__((address_space(3))) unsigned int*)(l), 16, 0, 0)

// ---- prep: Tb bf16 downcast; Vt[b][d][s] bf16 transpose; zero done ctrs ----
__global__ void prep_kernel(const float* __restrict__ V, const float* __restrict__ T,
                            __bf16* __restrict__ Vt, __bf16* __restrict__ Tb,
                            int* __restrict__ done) {
    __shared__ float tile[64][65];
    int bid = blockIdx.x;                      // 1024 blocks
    int tid = threadIdx.x;                     // 256 threads
    if (bid == 0 && tid < 128) done[tid] = 0;
    int b  = bid >> 6;
    int t2 = bid & 63;

    {   // T downcast: rows [t2*32, t2*32+32) of batch b; 16 f32 per thread
        int flat = tid * 16;
        int r = flat >> 7, cc = flat & 127;
        const float* p = T + ((size_t)b * S_LEN + t2 * 32 + r) * D_DIM + cc;
        __bf16* q = Tb + ((size_t)b * S_LEN + t2 * 32 + r) * D_DIM + cc;
        bf16x8 w0, w1;
        f32x4 a0 = *(const f32x4*)p,       a1 = *(const f32x4*)(p + 4);
        f32x4 a2 = *(const f32x4*)(p + 8), a3 = *(const f32x4*)(p + 12);
        #pragma unroll
        for (int j = 0; j < 4; ++j) {
            w0[j] = (__bf16)a0[j]; w0[4 + j] = (__bf16)a1[j];
            w1[j] = (__bf16)a2[j]; w1[4 + j] = (__bf16)a3[j];
        }
        *(bf16x8*)q = w0;
        *(bf16x8*)(q + 8) = w1;
    }

    int s0 = (t2 >> 1) * 64;
    int d0 = (t2 & 1) * 64;
    #pragma unroll
    for (int it = 0; it < 2; ++it) {
        int row = it * 32 + (tid >> 3);
        int c   = (tid & 7) * 8;
        const float* p = V + ((size_t)b * S_LEN + s0 + row) * D_DIM + d0 + c;
        *(f32x4*)(&tile[row][c])     = *(const f32x4*)p;
        *(f32x4*)(&tile[row][c + 4]) = *(const f32x4*)(p + 4);
    }
    __syncthreads();
    #pragma unroll
    for (int it = 0; it < 2; ++it) {
        int dr = it * 32 + (tid >> 3);
        int c  = (tid & 7) * 8;
        bf16x8 w;
        #pragma unroll
        for (int j = 0; j < 8; ++j) w[j] = (__bf16)tile[c + j][dr];
        *(bf16x8*)(Vt + ((size_t)b * D_DIM + d0 + dr) * S_LEN + s0 + c) = w;
    }
}

// ---------------- Flash attention, causal + threshold, fixed-max ----------------
// 512 threads = 8 waves, 128 q-rows per block. LDS 131072 B => 1 block/CU:
//   [     0,  49152)  Tt x3: 64 rows x 256B each, XOR-swizzled via DMA source
//   [ 49152,  98304)  Vl x3: 128 rows x 128B each, XOR-swizzled via DMA source
//   [ 98304, 131072)  P x2: [128 q][128B keys], swizzled. P0 doubles as
//                     Lx[8][64] f32 cross-wave l-reduction buffer between segs.
__global__ __launch_bounds__(512, 2)
void fa_kernel(const float* __restrict__ Q, const __bf16* __restrict__ Tb,
               const __bf16* __restrict__ Vt, float* __restrict__ O,
               float* __restrict__ pO, float* __restrict__ pL,
               int* __restrict__ done) {
    __shared__ __align__(16) unsigned char smem[131072];

    const int bid = blockIdx.x;          // 256 = b(4b) | pair(3b) | chunk(1b)
    const int b   = bid & 15;
    const int pi  = (bid >> 4) & 7;      // pair: q-tiles (pi, 15-pi), 128 rows
    const int c   = bid >> 7;            // chunk 0/1 of the 34-tile enumeration
    const int Lt  = 2 * pi + 2;          // light k-tile count (2..16)
    const int pr  = b * 8 + pi;
    const int jqL = pi, jqH = 15 - pi;

    const int tid  = threadIdx.x;
    const int lane = tid & 63;
    const int wv   = tid >> 6;           // 0..7
    const int col  = lane & 15;
    const int quad = lane >> 4;
    const int kg   = wv & 3;             // key-group (S) / d-group (PV)
    const int h    = wv >> 2;            // q-half

    float* Lxf = (float*)(smem + 98304);

    const __bf16* TbB = Tb + (size_t)b * (S_LEN * D_DIM);
    const __bf16* VtB = Vt + (size_t)b * (D_DIM * S_LEN);

    // per-thread pre-swizzled global source offsets; 2 T + 2 V DMA per wave
    int toff[2], voff[2];
    #pragma unroll
    for (int i = 0; i < 2; ++i) {
        int trw = wv * 8 + i * 4 + quad;
        toff[i] = trw * 128 + (((lane & 15) ^ (trw & 7)) << 3);
        int drw = wv * 16 + i * 8 + (lane >> 3);
        voff[i] = drw * 2048 + (((lane & 7) ^ (drw & 7)) << 3);
    }

    auto issueTile = [&](int k0, int buf) {
        const __bf16* ts = TbB + (size_t)k0 * D_DIM;
        const __bf16* vs = VtB + k0;
        unsigned char* lt = smem + buf * 16384 + wv * 2048;
        unsigned char* lv = smem + 49152 + buf * 16384 + wv * 2048;
        GLD16(ts + toff[0], lt);
        GLD16(ts + toff[1], lt + 1024);
        GLD16(vs + voff[0], lv);
        GLD16(vs + voff[1], lv + 1024);
    };

    // Q as B-frags for the wave's 64 q-rows (q = 64h + 16t + col): 64 VGPRs
    bf16x8 qf[4][4];
    auto loadQ = [&](int jq) {
        #pragma unroll
        for (int t = 0; t < 4; ++t) {
            const float* qptr = Q + ((size_t)b * S_LEN + jq * 128 + h * 64 + 16 * t + col) * D_DIM + quad * 8;
            #pragma unroll
            for (int kk = 0; kk < 4; ++kk) {
                f32x4 a = *(const f32x4*)(qptr + kk * 32);
                f32x4 d = *(const f32x4*)(qptr + kk * 32 + 4);
                #pragma unroll
                for (int j = 0; j < 4; ++j) { qf[t][kk][j] = (__bf16)a[j]; qf[t][kk][4 + j] = (__bf16)d[j]; }
            }
        }
    };

    f32x4 oacc[4][2];     // [t][dn][r]: q = 64h+16t+quad*4+r, d = 32kg+16dn+col
    float lsum[4];        // per-lane partial l for q = 64h+16t+col (wave's 16 keys)
    float lfull[4][4];    // after finishSeg: full l for q = 64h+16t+quad*4+r

    auto computeTile = [&](unsigned char* Tt, unsigned char* Vl, unsigned char* Pb, int dKt) {
        // ---- S: wave's 16 keys (16kg..16kg+15) x its 64 q. A=T-frag, B=qf ----
        f32x4 sacc[4];
        #pragma unroll
        for (int t = 0; t < 4; ++t) sacc[t] = {0.f, 0.f, 0.f, 0.f};
        __builtin_amdgcn_s_setprio(1);
        #pragma unroll
        for (int kk = 0; kk < 4; ++kk) {
            int trow = kg * 16 + col;
            bf16x8 tf = *(const bf16x8*)(Tt + trow * 256 + ((kk * 64 + quad * 16) ^ ((trow & 7) << 4)));
            #pragma unroll
            for (int t = 0; t < 4; ++t)
                sacc[t] = __builtin_amdgcn_mfma_f32_16x16x32_bf16(tf, qf[t][kk], sacc[t], 0, 0, 0);
        }
        __builtin_amdgcn_s_setprio(0);

        // D[m = keyloc = 16kg+quad*4+r][n = q = 64h+16t+col]
        float p[4][4];
        #pragma unroll
        for (int t = 0; t < 4; ++t)
            #pragma unroll
            for (int r = 0; r < 4; ++r) {
                float s = sacc[t][r];
                float e = __expf(s * SCALE);
                p[t][r] = (s > THRESH) ? e : 1.0f;
            }
        if (dKt < 64) {                      // diag pair of tiles only
            #pragma unroll
            for (int t = 0; t < 4; ++t)
                #pragma unroll
                for (int r = 0; r < 4; ++r)
                    if (kg * 16 + quad * 4 + r - (h * 64 + 16 * t + col) > dKt) p[t][r] = 0.0f;
        }
        #pragma unroll
        for (int t = 0; t < 4; ++t)
            lsum[t] += (p[t][0] + p[t][1]) + (p[t][2] + p[t][3]);

        // P[q][key]: key axis = r => one ds_write_b64 per t
        #pragma unroll
        for (int t = 0; t < 4; ++t) {
            int row = h * 64 + 16 * t + col;
            bf16x4 w = {(__bf16)p[t][0], (__bf16)p[t][1], (__bf16)p[t][2], (__bf16)p[t][3]};
            *(bf16x4*)(Pb + row * 128 + ((kg * 32 + quad * 8) ^ ((row & 7) << 4))) = w;
        }
        asm volatile("s_waitcnt lgkmcnt(0)" ::: "memory");  // P writes drained
        __builtin_amdgcn_s_barrier();                       // b2: P visible

        // ---- PV: wave's 32 d (32kg..) x its 64 q. A=P-frag, B=V-frag ----
        __builtin_amdgcn_s_setprio(1);
        #pragma unroll
        for (int kb = 0; kb < 2; ++kb) {
            bf16x8 pf[4];
            #pragma unroll
            for (int t = 0; t < 4; ++t) {
                int prow = h * 64 + 16 * t + col;
                pf[t] = *(const bf16x8*)(Pb + prow * 128 + ((kb * 64 + quad * 16) ^ ((prow & 7) << 4)));
            }
            #pragma unroll
            for (int dn = 0; dn < 2; ++dn) {
                int vrow = kg * 32 + 16 * dn + col;
                bf16x8 vf = *(const bf16x8*)(Vl + vrow * 128 + ((kb * 64 + quad * 16) ^ ((vrow & 7) << 4)));
                #pragma unroll
                for (int t = 0; t < 4; ++t)
                    oacc[t][dn] = __builtin_amdgcn_mfma_f32_16x16x32_bf16(pf[t], vf, oacc[t][dn], 0, 0, 0);
            }
        }
        __builtin_amdgcn_s_setprio(0);
    };

    auto runSeg = [&](int jq, int k0t, int nt) {
        loadQ(jq);
        #pragma unroll
        for (int t = 0; t < 4; ++t) {
            oacc[t][0] = {0.f, 0.f, 0.f, 0.f};
            oacc[t][1] = {0.f, 0.f, 0.f, 0.f};
            lsum[t] = 0.f;
        }
        issueTile(k0t * 64, 0);
        if (nt > 1) issueTile((k0t + 1) * 64, 1);
        int cb = 0;
        for (int s = 0; s < nt; ++s) {
            if (s + 1 < nt) {
                asm volatile("s_waitcnt vmcnt(4)" ::: "memory");  // tile s landed; s+1 in flight
            } else {
                asm volatile("s_waitcnt vmcnt(0)" ::: "memory");
            }
            __builtin_amdgcn_s_barrier();                         // b1: tile s staged by all
            if (s + 2 < nt) {                                     // safe: buf (s+2)%3's readers done
                int nb = cb + 2; if (nb >= 3) nb -= 3;
                issueTile((k0t + s + 2) * 64, nb);
            }
            computeTile(smem + cb * 16384, smem + 49152 + cb * 16384,
                        smem + 98304 + (s & 1) * 16384, 128 * jq - 64 * (k0t + s));
            cb = (cb == 2) ? 0 : cb + 1;
        }
    };

    // cross-wave l reduction through Lx[8][64] (P0 region), once per segment
    auto finishSeg = [&]() {
        __syncthreads();                   // all waves past last PV (P0 may be live)
        #pragma unroll
        for (int t = 0; t < 4; ++t) {
            float lw = lsum[t];
            lw += __shfl_xor(lw, 16);
            lw += __shfl_xor(lw, 32);      // sum over quads -> wave-l for q=64h+16t+col
            if (quad == 0) Lxf[wv * 64 + 16 * t + col] = lw;
        }
        __syncthreads();
        #pragma unroll
        for (int t = 0; t < 4; ++t)
            #pragma unroll
            for (int r = 0; r < 4; ++r) {
                int q16 = 16 * t + quad * 4 + r;   // within this wave's q-half
                lfull[t][r] = (Lxf[(4 * h + 0) * 64 + q16] + Lxf[(4 * h + 1) * 64 + q16]) +
                              (Lxf[(4 * h + 2) * 64 + q16] + Lxf[(4 * h + 3) * 64 + q16]);
            }
        __syncthreads();                   // Lx free before next seg's P writes
    };

    auto storeO = [&](int jq) {
        float* optr = O + ((size_t)b * S_LEN + jq * 128 + h * 64) * D_DIM + kg * 32;
        #pragma unroll
        for (int t = 0; t < 4; ++t)
            #pragma unroll
            for (int r = 0; r < 4; ++r) {
                float inv = 1.0f / lfull[t][r];
                #pragma unroll
                for (int dn = 0; dn < 2; ++dn)
                    optr[(16 * t + quad * 4 + r) * D_DIM + 16 * dn + col] = oacc[t][dn][r] * inv;
            }
    };

    auto storePartial = [&]() {
        float* po = pO + (size_t)pr * (128 * 128);
        float* pl = pL + (size_t)pr * 128;
        #pragma unroll
        for (int t = 0; t < 4; ++t)
            #pragma unroll
            for (int r = 0; r < 4; ++r)
                #pragma unroll
                for (int dn = 0; dn < 2; ++dn)
                    po[(h * 64 + 16 * t + quad * 4 + r) * 128 + kg * 32 + 16 * dn + col] = oacc[t][dn][r];
        if (kg == 0 && col == 0) {
            #pragma unroll
            for (int t = 0; t < 4; ++t)
                #pragma unroll
                for (int r = 0; r < 4; ++r)
                    pl[h * 64 + 16 * t + quad * 4 + r] = lfull[t][r];
        }
        __threadfence();
        __syncthreads();
        if (tid == 0)
            __hip_atomic_fetch_add(&done[pr], 1, __ATOMIC_RELEASE, __HIP_MEMORY_SCOPE_AGENT);
    };

    auto addPartial = [&]() {
        if (tid == 0) {
            while (__hip_atomic_load(&done[pr], __ATOMIC_ACQUIRE, __HIP_MEMORY_SCOPE_AGENT) < 1)
                __builtin_amdgcn_s_sleep(8);
        }
        __syncthreads();
        __threadfence();
        const float* po = pO + (size_t)pr * (128 * 128);
        const float* pl = pL + (size_t)pr * 128;
        #pragma unroll
        for (int t = 0; t < 4; ++t)
            #pragma unroll
            for (int r = 0; r < 4; ++r) {
                #pragma unroll
                for (int dn = 0; dn < 2; ++dn)
                    oacc[t][dn][r] += po[(h * 64 + 16 * t + quad * 4 + r) * 128 + kg * 32 + 16 * dn + col];
                lfull[t][r] += pl[h * 64 + 16 * t + quad * 4 + r];
            }
    };

    // ---- chunk schedule over the 34-tile pair enumeration [0,17,34) ----
    if (c == 0) {
        runSeg(jqL, 0, Lt);                 // light, complete
        finishSeg();
        storeO(jqL);
        runSeg(jqH, 0, 17 - Lt);            // heavy prefix (1..15 tiles, no diag)
        finishSeg();
        storePartial();
    } else {
        runSeg(jqH, 17 - Lt, 17);           // heavy suffix incl. diag pair
        finishSeg();
        addPartial();                       // spin for c0's prefix partial
        storeO(jqH);
    }
}

extern "C" void kernel_launch(void* const* d_in, const int* in_sizes, int n_in,
                              void* d_out, int out_size, void* d_ws, size_t ws_size,
                              hipStream_t stream) {
    const float* Q = (const float*)d_in[0];
    const float* T = (const float*)d_in[1];
    const float* V = (const float*)d_in[2];
    float* O = (float*)d_out;

    // ws: Vt 8MB | Tb 8MB | pO 8MB (128 pairs x 128x128 f32) | pL 64KB | done 512B
    unsigned char* ws = (unsigned char*)d_ws;
    __bf16* Vt = (__bf16*)ws;
    __bf16* Tb = (__bf16*)(ws + 8388608);
    float*  pO = (float*)(ws + 16777216);
    float*  pL = (float*)(ws + 16777216 + 8388608);
    int*  done = (int*)(ws + 16777216 + 8388608 + 65536);

    prep_kernel<<<1024, 256, 0, stream>>>(V, T, Vt, Tb, done);
    fa_kernel<<<256, 512, 0, stream>>>(Q, Tb, Vt, O, pO, pL, done);
}